// Round 1
// 473.764 us; speedup vs baseline: 1.2797x; 1.2797x over previous
//
#include <hip/hip_runtime.h>
#include <hip/hip_bf16.h>

// Problem constants (from reference setup_inputs)
#define M_TOK 8192
#define N_OUT 4096
#define K_IN  4096

#define SPARSIFY_BLOCKS 2048

typedef __attribute__((ext_vector_type(8))) __bf16 bf16x8;
typedef __attribute__((ext_vector_type(4))) float f32x4;

__device__ __forceinline__ unsigned short f2bf(float f) {
    return __builtin_bit_cast(unsigned short, (__bf16)f);
}

// ---------------------------------------------------------------------------
// Kernel 1: soft-threshold 2:4 sparsify along K, write bf16 W_s.
// Grid-stride, 2048 blocks; per-block partial sums written to pd/ps.
// ---------------------------------------------------------------------------
__global__ __launch_bounds__(256) void sparsify_kernel(
        const float* __restrict__ w,
        unsigned short* __restrict__ wsb,
        float* __restrict__ pd,
        float* __restrict__ ps,
        int ngroups) {
    const int stride = gridDim.x * blockDim.x;
    float dsq = 0.0f, ssq = 0.0f;
    for (int gid = blockIdx.x * blockDim.x + threadIdx.x; gid < ngroups;
         gid += stride) {
        const float4 g = ((const float4*)w)[gid];
        float a0 = fabsf(g.x), a1 = fabsf(g.y), a2 = fabsf(g.z), a3 = fabsf(g.w);
        float lo1 = fminf(a0, a1), hi1 = fmaxf(a0, a1);
        float lo2 = fminf(a2, a3), hi2 = fmaxf(a2, a3);
        float t = fminf(fmaxf(lo1, lo2), fminf(hi1, hi2));
        float s0 = (a0 > t) ? copysignf(a0 - t, g.x) : 0.0f;
        float s1 = (a1 > t) ? copysignf(a1 - t, g.y) : 0.0f;
        float s2 = (a2 > t) ? copysignf(a2 - t, g.z) : 0.0f;
        float s3 = (a3 > t) ? copysignf(a3 - t, g.w) : 0.0f;
        dsq += g.x * g.x + g.y * g.y + g.z * g.z + g.w * g.w;
        ssq += s0 * s0 + s1 * s1 + s2 * s2 + s3 * s3;
        ushort4 o;
        o.x = f2bf(s0); o.y = f2bf(s1); o.z = f2bf(s2); o.w = f2bf(s3);
        ((ushort4*)wsb)[gid] = o;
    }
    for (int off = 32; off > 0; off >>= 1) {
        dsq += __shfl_down(dsq, off);
        ssq += __shfl_down(ssq, off);
    }
    __shared__ float sd[4], ss[4];
    int lane = threadIdx.x & 63, wv = threadIdx.x >> 6;
    if (lane == 0) { sd[wv] = dsq; ss[wv] = ssq; }
    __syncthreads();
    if (threadIdx.x == 0) {
        pd[blockIdx.x] = sd[0] + sd[1] + sd[2] + sd[3];
        ps[blockIdx.x] = ss[0] + ss[1] + ss[2] + ss[3];
    }
}

// ---------------------------------------------------------------------------
// Kernel 2: reduce partials -> scale
// ---------------------------------------------------------------------------
__global__ __launch_bounds__(256) void scale_kernel(
        const float* __restrict__ pd,
        const float* __restrict__ ps,
        float* __restrict__ sums) {
    float d = 0.0f, s = 0.0f;
#pragma unroll
    for (int k = 0; k < SPARSIFY_BLOCKS / 256; k++) {
        d += pd[threadIdx.x + k * 256];
        s += ps[threadIdx.x + k * 256];
    }
    for (int off = 32; off > 0; off >>= 1) {
        d += __shfl_down(d, off);
        s += __shfl_down(s, off);
    }
    __shared__ float sd[4], ss[4];
    int lane = threadIdx.x & 63, wv = threadIdx.x >> 6;
    if (lane == 0) { sd[wv] = d; ss[wv] = s; }
    __syncthreads();
    if (threadIdx.x == 0) {
        float dt = sd[0] + sd[1] + sd[2] + sd[3];
        float st = fmaxf(ss[0] + ss[1] + ss[2] + ss[3], 1e-12f);
        float sc = sqrtf(dt / st);
        sums[2] = fminf(fmaxf(sc, 0.1f), 10.0f);
    }
}

// ---------------------------------------------------------------------------
// Kernel 3: x fp32 -> bf16
// ---------------------------------------------------------------------------
__global__ __launch_bounds__(256) void convx_kernel(
        const float* __restrict__ x,
        unsigned short* __restrict__ xb,
        int n4) {
    int i = blockIdx.x * blockDim.x + threadIdx.x;
    if (i < n4) {
        float4 v = ((const float4*)x)[i];
        ushort4 o;
        o.x = f2bf(v.x); o.y = f2bf(v.y); o.z = f2bf(v.z); o.w = f2bf(v.w);
        ((ushort4*)xb)[i] = o;
    }
}

// ---------------------------------------------------------------------------
// Kernel 4: 256x256-tile 8-phase GEMM (m201-style template, plain HIP).
// C[M][N] = scale * (A[M][K] @ B[N][K]^T) + bias[N]
//
//  - BM=BN=256, BK=64, 8 waves (2M x 4N), per-wave output 128x64.
//  - LDS 128 KiB: 2 buffers x (A 32 KiB + B 32 KiB). Each operand tile is
//    2 half-tiles of [128][64] bf16, stored as contiguous [16][32] subtiles
//    (1024 B) with the st_16x32 swizzle: byte ^= ((byte>>9)&1)<<5.
//    global_load_lds writes linearly; the swizzle is applied by permuting the
//    per-lane GLOBAL source address (inverse == forward, involution), and on
//    the ds_read byte address.  (rule #21: both-sides-or-neither)
//  - 4 phases per K-tile: {ds_read frags, prefetch 1 half-tile, barrier,
//    setprio(1) 16 MFMA setprio(0), barrier}. A-frags all read in P0; B nfrag
//    p read one phase early. Prefetch stream runs 7 half-tiles ahead of
//    compute; vmcnt(6) once per K-tile keeps 3 half-tiles in flight across
//    barriers (never drains to 0 in the main loop).
//  - Anti-overwrite: a half-tile prefetch into the CURRENT buffer is only
//    issued >=1 full phase (2 barriers) after the last lgkmcnt-pinned ds_read
//    of that region, so cross-wave reads always complete first.
// ---------------------------------------------------------------------------
#define BM 256
#define BN 256
#define BK 64
#define NT (K_IN / BK)   // 64 K-tiles

#define GBAR() do { asm volatile("" ::: "memory"); \
                    __builtin_amdgcn_s_barrier();  \
                    asm volatile("" ::: "memory"); } while (0)

// HT: 0=A.h0 1=A.h1 2=B.h0 3=B.h1 (must be a literal). Element offsets:
// buf stride 32768, B region +16384, half +8192, load1 +4096, wave +512.
#define STAGE(GP, O0, O1, HT, TAU)                                             \
  do {                                                                         \
    const int _t = (TAU);                                                      \
    unsigned short* _d = smem + ((_t & 1) << 15) + (((HT) >> 1) << 14) +       \
                         (((HT) & 1) << 13) + (wv << 9);                       \
    __builtin_amdgcn_global_load_lds(                                          \
        (const __attribute__((address_space(1))) void*)((GP) + (O0) + _t * 64),\
        (__attribute__((address_space(3))) void*)_d, 16, 0, 0);                \
    __builtin_amdgcn_global_load_lds(                                          \
        (const __attribute__((address_space(1))) void*)((GP) + (O1) + _t * 64),\
        (__attribute__((address_space(3))) void*)(_d + 4096), 16, 0, 0);       \
  } while (0)

#define STRIP(P, BF)                                                           \
  do {                                                                         \
    __builtin_amdgcn_s_setprio(1);                                             \
    _Pragma("unroll")                                                          \
    for (int mi = 0; mi < 8; ++mi) {                                           \
      acc[mi][P] = __builtin_amdgcn_mfma_f32_16x16x32_bf16(                    \
          a[mi][0], BF[0], acc[mi][P], 0, 0, 0);                               \
      acc[mi][P] = __builtin_amdgcn_mfma_f32_16x16x32_bf16(                    \
          a[mi][1], BF[1], acc[mi][P], 0, 0, 0);                               \
    }                                                                          \
    __builtin_amdgcn_s_setprio(0);                                             \
  } while (0)

__global__ __launch_bounds__(512, 2) void gemm_8phase_kernel(
        const unsigned short* __restrict__ A,   // xb  bf16 [M][K]
        const unsigned short* __restrict__ B,   // wsb bf16 [N][K]
        const float* __restrict__ bias,         // [N]
        const float* __restrict__ sums,         // sums[2] = scale
        float* __restrict__ C) {                // [M][N]
    __shared__ __align__(16) unsigned short smem[65536];  // 128 KiB

    const int tid  = threadIdx.x;          // 0..511
    const int lane = tid & 63;
    const int wv   = tid >> 6;             // 0..7
    const int wm   = wv >> 2;              // 0..1  (M half)
    const int wn   = wv & 3;               // 0..3  (N quarter)
    const int quad = lane >> 4;
    const int l16  = lane & 15;

    // XCD-aware bijective swizzle: 512 wgs, 512 % 8 == 0
    const int nwg = (M_TOK / BM) * (N_OUT / BN);          // 512
    const int swz = (blockIdx.x & 7) * (nwg >> 3) + (blockIdx.x >> 3);
    const int m0 = (swz >> 4) * BM;                       // 32 M-tiles
    const int n0 = (swz & 15) * BN;                       // 16 N-tiles

    // --- per-thread staging source map (inverse st_16x32 swizzle) ---------
    // Half-tile = 16 KiB, staged linearly as 1024 chunks of 16 B.
    // Physical chunk idx -> logical (row, col) within the [128][64] half.
    unsigned offA[2][2], offB[2][2];       // [half][load_i], element offsets
#pragma unroll
    for (int i = 0; i < 2; ++i) {
        const int idx = i * 512 + tid;                    // 0..1023
        const int s   = idx >> 6;                         // subtile 0..15
        const int bb  = (idx & 63) << 4;                  // byte in subtile
        const int bl  = bb ^ (((bb >> 9) & 1) << 5);      // logical byte
        const int row = (s >> 1) * 16 + (bl >> 6);        // 0..127
        const int col = (s & 1) * 32 + ((bl & 63) >> 1);  // 0,8,..,56
#pragma unroll
        for (int h = 0; h < 2; ++h) {
            offA[h][i] = (unsigned)(m0 + h * 128 + row) * K_IN + col;
            offB[h][i] = (unsigned)(n0 + h * 128 + row) * K_IN + col;
        }
    }

    // --- per-thread ds_read addressing (swizzled) -------------------------
    // frag (r = blk*16 + l16, c = ks*32 + quad*8): subtile blk*2+ks,
    // inner byte (l16*64 + quad*16) ^ ((l16>>3)&1)<<5.
    const unsigned innerE =
        (unsigned)(((l16 * 64 + quad * 16) ^ (((l16 >> 3) & 1) << 5)) >> 1);
    const unsigned aoff = (unsigned)(wm << 13) + innerE;
    const unsigned boff = 16384u + ((wn >> 1) << 13) + ((wn & 1) << 12) + innerE;

    f32x4 acc[8][4] = {};

    // --- prologue: stage tile0 (4 halves) + tile1 A0,A1,B0 ----------------
    STAGE(A, offA[0][0], offA[0][1], 0, 0);
    STAGE(A, offA[1][0], offA[1][1], 1, 0);
    STAGE(B, offB[0][0], offB[0][1], 2, 0);
    STAGE(B, offB[1][0], offB[1][1], 3, 0);
    STAGE(A, offA[0][0], offA[0][1], 0, 1);
    STAGE(A, offA[1][0], offA[1][1], 1, 1);
    STAGE(B, offB[0][0], offB[0][1], 2, 1);
    asm volatile("s_waitcnt vmcnt(6)" ::: "memory");  // tile0 landed, 3 in flight
    GBAR();

    for (int t = 0; t < NT; ++t) {
        const unsigned bufo = (unsigned)((t & 1) << 15);
        const unsigned ba = bufo + aoff;
        const unsigned bb = bufo + boff;
        bf16x8 a[8][2], b0[2], b1[2], b2[2], b3[2];

        // ---- phase 0: all A frags + B n0,n1; prefetch (t+1).B1 (other buf)
#pragma unroll
        for (int mi = 0; mi < 8; ++mi) {
            a[mi][0] = *(const bf16x8*)(smem + ba + (mi << 10));
            a[mi][1] = *(const bf16x8*)(smem + ba + (mi << 10) + 512);
        }
        b0[0] = *(const bf16x8*)(smem + bb);
        b0[1] = *(const bf16x8*)(smem + bb + 512);
        b1[0] = *(const bf16x8*)(smem + bb + 1024);
        b1[1] = *(const bf16x8*)(smem + bb + 1536);
        if (t < NT - 1) STAGE(B, offB[1][0], offB[1][1], 3, t + 1);
        GBAR();
        STRIP(0, b0);
        GBAR();

        // ---- phase 1: B n2; prefetch (t+2).A0 (curr buf, A reads done @P0)
        b2[0] = *(const bf16x8*)(smem + bb + 2048);
        b2[1] = *(const bf16x8*)(smem + bb + 2560);
        if (t < NT - 2) STAGE(A, offA[0][0], offA[0][1], 0, t + 2);
        GBAR();
        STRIP(1, b1);
        GBAR();

        // ---- phase 2: B n3; prefetch (t+2).A1
        b3[0] = *(const bf16x8*)(smem + bb + 3072);
        b3[1] = *(const bf16x8*)(smem + bb + 3584);
        if (t < NT - 2) STAGE(A, offA[1][0], offA[1][1], 1, t + 2);
        GBAR();
        STRIP(2, b2);
        GBAR();

        // ---- phase 3: prefetch (t+2).B0 (B reads finished @P2)
        if (t < NT - 2) STAGE(B, offB[0][0], offB[0][1], 2, t + 2);
        GBAR();
        STRIP(3, b3);
        if (t == NT - 2) asm volatile("s_waitcnt vmcnt(0)" ::: "memory");
        else             asm volatile("s_waitcnt vmcnt(6)" ::: "memory");
        GBAR();
    }

    // --- epilogue: scale + bias, fp32 store -------------------------------
    const float scale = sums[2];
#pragma unroll
    for (int p = 0; p < 4; ++p) {
        const int col = n0 + wn * 64 + p * 16 + l16;
        const float bv = bias[col];
#pragma unroll
        for (int mi = 0; mi < 8; ++mi) {
#pragma unroll
            for (int r = 0; r < 4; ++r) {
                const int row = m0 + wm * 128 + mi * 16 + quad * 4 + r;
                C[(size_t)row * N_OUT + col] = scale * acc[mi][p][r] + bv;
            }
        }
    }
}

// ---------------------------------------------------------------------------
// Launch
// ---------------------------------------------------------------------------
extern "C" void kernel_launch(void* const* d_in, const int* in_sizes, int n_in,
                              void* d_out, int out_size, void* d_ws, size_t ws_size,
                              hipStream_t stream) {
    const float* x      = (const float*)d_in[0];   // [8192][4096]
    const float* weight = (const float*)d_in[1];   // [4096][4096]
    const float* bias   = (const float*)d_in[2];   // [4096]
    float* out          = (float*)d_out;           // [8192][4096]

    char* ws = (char*)d_ws;
    float* sums         = (float*)ws;                         // 3 floats @ 0
    float* pd           = (float*)(ws + 1024);                // 2048 floats
    float* psm          = (float*)(ws + 1024 + 4 * SPARSIFY_BLOCKS);
    unsigned short* wsb = (unsigned short*)(ws + 32768);      // 32 MB bf16 W_s
    unsigned short* xb  = (unsigned short*)(ws + 32768 + (size_t)N_OUT * K_IN * 2); // 64 MB bf16 x

    // 1) sparsify + per-block partials
    const int ngroups = N_OUT * K_IN / 4;
    sparsify_kernel<<<SPARSIFY_BLOCKS, 256, 0, stream>>>(weight, wsb, pd, psm, ngroups);

    // 2) reduce partials + scale
    scale_kernel<<<1, 256, 0, stream>>>(pd, psm, sums);

    // 3) x -> bf16
    const int n4 = M_TOK * K_IN / 4;
    convx_kernel<<<n4 / 256, 256, 0, stream>>>(x, xb, n4);

    // 4) 256^2 8-phase GEMM + epilogue
    const int nwg = (M_TOK / BM) * (N_OUT / BN);   // 512
    gemm_8phase_kernel<<<dim3(nwg), dim3(512), 0, stream>>>(xb, wsb, bias, sums, out);
}